// Round 1
// baseline (5974.500 us; speedup 1.0000x reference)
//
#include <hip/hip_runtime.h>
#include <math.h>

#define NB 16384
#define DIN 768

// ---------------- small kernels ----------------

__global__ void k_zero2(float* a, float* b) {
    if (threadIdx.x == 0) { *a = 0.f; *b = 0.f; }
}

__global__ void k_norm(const float* __restrict__ x, const float* __restrict__ m,
                       const float* __restrict__ s, float* __restrict__ xn) {
    int i = blockIdx.x * 256 + threadIdx.x;          // 16384*768 total
    int j = i % DIN;
    xn[i] = (x[i] - m[j]) / s[j];
}

// one 64-lane wave per codebook row (4 rows / 256-thread block)
__global__ void k_cbnorm(const float* __restrict__ cb, float* __restrict__ cbn) {
    int row = blockIdx.x * 4 + (threadIdx.x >> 6);
    int lane = threadIdx.x & 63;
    const float* p = cb + (size_t)row * 128;
    float v0 = p[lane], v1 = p[lane + 64];
    float s = v0 * v0 + v1 * v1;
    #pragma unroll
    for (int m = 32; m >= 1; m >>= 1) s += __shfl_xor(s, m, 64);
    if (lane == 0) cbn[row] = s;
}

// ---------------- fused Linear + ReLU + RMSNorm ----------------
// block = 32 rows x N cols; threads (tx=32, ty=8); per-thread 4 rows x N/32 cols
template <int N>
__global__ __launch_bounds__(256, 2) void k_lin_relu_rms(
    const float* __restrict__ A, const float* __restrict__ W,
    const float* __restrict__ bias, const float* __restrict__ g,
    float* __restrict__ out, int K) {
    constexpr int CJ = N / 32;
    __shared__ float Asub[32][17];
    __shared__ float Wsub[16][N];
    __shared__ float rsums[32];
    const int tid = threadIdx.x;
    const int tx = tid & 31, ty = tid >> 5;
    const int row0 = blockIdx.x * 32;

    float acc[4][CJ];
    #pragma unroll
    for (int r = 0; r < 4; r++)
        #pragma unroll
        for (int j = 0; j < CJ; j++) acc[r][j] = 0.f;

    for (int k0 = 0; k0 < K; k0 += 16) {
        for (int e = tid; e < 512; e += 256) {
            int r = e >> 4, kk = e & 15;
            Asub[r][kk] = A[(size_t)(row0 + r) * K + k0 + kk];
        }
        constexpr int NW4 = 16 * N / 4;
        for (int e = tid; e < NW4; e += 256) {
            int kk = e / (N / 4), c4 = e % (N / 4);
            *(float4*)&Wsub[kk][c4 * 4] = *(const float4*)&W[(size_t)(k0 + kk) * N + c4 * 4];
        }
        __syncthreads();
        #pragma unroll
        for (int kk = 0; kk < 16; kk++) {
            float a[4];
            #pragma unroll
            for (int r = 0; r < 4; r++) a[r] = Asub[ty * 4 + r][kk];
            #pragma unroll
            for (int j = 0; j < CJ; j++) {
                float w = Wsub[kk][tx + 32 * j];
                #pragma unroll
                for (int r = 0; r < 4; r++) acc[r][j] = fmaf(a[r], w, acc[r][j]);
            }
        }
        __syncthreads();
    }
    // bias + relu + per-row sum of squares
    float ss[4] = {0.f, 0.f, 0.f, 0.f};
    #pragma unroll
    for (int j = 0; j < CJ; j++) {
        float bb = bias[tx + 32 * j];
        #pragma unroll
        for (int r = 0; r < 4; r++) {
            float v = acc[r][j] + bb;
            v = v > 0.f ? v : 0.f;
            acc[r][j] = v;
            ss[r] = fmaf(v, v, ss[r]);
        }
    }
    #pragma unroll
    for (int m = 1; m < 32; m <<= 1)
        #pragma unroll
        for (int r = 0; r < 4; r++) ss[r] += __shfl_xor(ss[r], m, 64);
    if (tx == 0)
        #pragma unroll
        for (int r = 0; r < 4; r++) rsums[ty * 4 + r] = ss[r];
    __syncthreads();
    constexpr float invN = 1.0f / (float)N;
    #pragma unroll
    for (int r = 0; r < 4; r++) {
        float scale = 1.0f / sqrtf(rsums[ty * 4 + r] * invN + 1e-6f);
        #pragma unroll
        for (int j = 0; j < CJ; j++) {
            int col = tx + 32 * j;
            out[(size_t)(row0 + ty * 4 + r) * N + col] = acc[r][j] * scale * g[col];
        }
    }
}

// ---------------- VQ: exact fp32 score + argmin ----------------
// block = 64 rows x all 8192 codes; threads (tx=16, ty=16); micro 4 rows x 8 codes.
// s_k = ||E_k||^2 - 2*r.E_k (row-constant ||r||^2 dropped; argmin-equivalent)
__global__ __launch_bounds__(256, 1) void k_vq_argmin(
    const float* __restrict__ R, const float* __restrict__ E,
    const float* __restrict__ cbn, int* __restrict__ idx_out,
    float* __restrict__ ids_f) {
    __shared__ float Rs[64][33];    // [row][k-chunk 32] +1 pad
    __shared__ float Es[128][33];   // [code][k-chunk 32] +1 pad
    const int tid = threadIdx.x;
    const int tx = tid & 15, ty = tid >> 4;
    const int row0 = blockIdx.x * 64;

    float best[4];
    int bidx[4];
    #pragma unroll
    for (int r = 0; r < 4; r++) { best[r] = 3.402823466e+38f; bidx[r] = 0; }

    for (int c0 = 0; c0 < 8192; c0 += 128) {
        float acc[4][8];
        #pragma unroll
        for (int r = 0; r < 4; r++)
            #pragma unroll
            for (int j = 0; j < 8; j++) acc[r][j] = 0.f;

        for (int k0 = 0; k0 < 128; k0 += 32) {
            __syncthreads();
            // stage R tile 64x32 (512 float4)
            for (int f = tid; f < 512; f += 256) {
                int r = f >> 3, k4 = f & 7;
                float4 v = *(const float4*)&R[(size_t)(row0 + r) * 128 + k0 + k4 * 4];
                int kb = k4 * 4;
                Rs[r][kb] = v.x; Rs[r][kb + 1] = v.y; Rs[r][kb + 2] = v.z; Rs[r][kb + 3] = v.w;
            }
            // stage E tile 128x32 (1024 float4)
            for (int f = tid; f < 1024; f += 256) {
                int c = f >> 3, k4 = f & 7;
                float4 v = *(const float4*)&E[(size_t)(c0 + c) * 128 + k0 + k4 * 4];
                int kb = k4 * 4;
                Es[c][kb] = v.x; Es[c][kb + 1] = v.y; Es[c][kb + 2] = v.z; Es[c][kb + 3] = v.w;
            }
            __syncthreads();
            #pragma unroll
            for (int k = 0; k < 32; k++) {
                float a[4];
                #pragma unroll
                for (int r = 0; r < 4; r++) a[r] = Rs[ty * 4 + r][k];
                #pragma unroll
                for (int j = 0; j < 8; j++) {
                    float e = Es[tx + 16 * j][k];
                    #pragma unroll
                    for (int r = 0; r < 4; r++) acc[r][j] = fmaf(a[r], e, acc[r][j]);
                }
            }
        }
        // running argmin (per-thread code order is ascending -> strict < keeps first)
        #pragma unroll
        for (int j = 0; j < 8; j++) {
            int c = c0 + tx + 16 * j;
            float cn = cbn[c];
            #pragma unroll
            for (int r = 0; r < 4; r++) {
                float s = fmaf(-2.f, acc[r][j], cn);
                if (s < best[r]) { best[r] = s; bidx[r] = c; }
            }
        }
    }
    // reduce across the 16 tx lanes; tie -> smaller index (numpy first-occurrence)
    #pragma unroll
    for (int m = 1; m < 16; m <<= 1) {
        #pragma unroll
        for (int r = 0; r < 4; r++) {
            float ob = __shfl_xor(best[r], m, 64);
            int oi = __shfl_xor(bidx[r], m, 64);
            if (ob < best[r] || (ob == best[r] && oi < bidx[r])) { best[r] = ob; bidx[r] = oi; }
        }
    }
    if (tx == 0) {
        #pragma unroll
        for (int r = 0; r < 4; r++) {
            int row = row0 + ty * 4 + r;
            idx_out[row] = bidx[r];
            ids_f[(size_t)row * 4] = (float)bidx[r];
        }
    }
}

// gather + residual update + qsum + vq_loss partial
__global__ void k_vq_update(const float* __restrict__ Rin, const int* __restrict__ idx,
                            const float* __restrict__ E, float* __restrict__ Rout,
                            float* __restrict__ qsum, float* __restrict__ vq_acc,
                            int firstq) {
    __shared__ float ps[4];
    int i = blockIdx.x * 256 + threadIdx.x;   // NB*128 total
    int row = i >> 7, d = i & 127;
    float e = E[(size_t)idx[row] * 128 + d];
    float rv = Rin[i] - e;
    Rout[i] = rv;
    qsum[i] = firstq ? e : (qsum[i] + e);
    float p = rv * rv;
    #pragma unroll
    for (int m = 1; m < 64; m <<= 1) p += __shfl_xor(p, m, 64);
    int lane = threadIdx.x & 63, w = threadIdx.x >> 6;
    if (lane == 0) ps[w] = p;
    __syncthreads();
    if (threadIdx.x == 0)
        atomicAdd(vq_acc, (ps[0] + ps[1] + ps[2] + ps[3]) * (1.25f / ((float)NB * 128.f)));
}

// ---------------- final Linear (512->768) + recon loss ----------------
// 64x64 tile; threads (16,16); micro 4x4. Reads xn from rec[], overwrites with recon.
__global__ __launch_bounds__(256, 2) void k_dec2(
    const float* __restrict__ A, const float* __restrict__ W,
    const float* __restrict__ bias, float* __restrict__ rec,
    float* __restrict__ loss_acc) {
    __shared__ float Asub[64][17];
    __shared__ float Wsub[16][64];
    __shared__ float red[4];
    const int tid = threadIdx.x;
    const int tx = tid & 15, ty = tid >> 4;
    const int row0 = blockIdx.x * 64, col0 = blockIdx.y * 64;
    float acc[4][4];
    #pragma unroll
    for (int r = 0; r < 4; r++)
        #pragma unroll
        for (int j = 0; j < 4; j++) acc[r][j] = 0.f;

    for (int k0 = 0; k0 < 512; k0 += 16) {
        for (int e = tid; e < 1024; e += 256) {
            int r = e >> 4, kk = e & 15;
            Asub[r][kk] = A[(size_t)(row0 + r) * 512 + k0 + kk];
        }
        {
            int kk = tid >> 4, c = tid & 15;
            *(float4*)&Wsub[kk][c * 4] = *(const float4*)&W[(size_t)(k0 + kk) * DIN + col0 + c * 4];
        }
        __syncthreads();
        #pragma unroll
        for (int kk = 0; kk < 16; kk++) {
            float a[4], w[4];
            #pragma unroll
            for (int r = 0; r < 4; r++) a[r] = Asub[ty * 4 + r][kk];
            #pragma unroll
            for (int j = 0; j < 4; j++) w[j] = Wsub[kk][tx + 16 * j];
            #pragma unroll
            for (int r = 0; r < 4; r++)
                #pragma unroll
                for (int j = 0; j < 4; j++) acc[r][j] = fmaf(a[r], w[j], acc[r][j]);
        }
        __syncthreads();
    }
    float lsum = 0.f;
    #pragma unroll
    for (int j = 0; j < 4; j++) {
        int col = col0 + tx + 16 * j;
        float bb = bias[col];
        #pragma unroll
        for (int r = 0; r < 4; r++) {
            int row = row0 + ty * 4 + r;
            float v = acc[r][j] + bb;
            size_t o = (size_t)row * DIN + col;
            float e = v - rec[o];     // rec holds xn here
            lsum = fmaf(e, e, lsum);
            rec[o] = v;
        }
    }
    #pragma unroll
    for (int m = 1; m < 64; m <<= 1) lsum += __shfl_xor(lsum, m, 64);
    int lane = tid & 63, w = tid >> 6;
    if (lane == 0) red[w] = lsum;
    __syncthreads();
    if (tid == 0)
        atomicAdd(loss_acc, (red[0] + red[1] + red[2] + red[3]) * (1.0f / ((float)NB * (float)DIN)));
}

// ---------------- launch ----------------

extern "C" void kernel_launch(void* const* d_in, const int* in_sizes, int n_in,
                              void* d_out, int out_size, void* d_ws, size_t ws_size,
                              hipStream_t stream) {
    (void)in_sizes; (void)n_in; (void)out_size; (void)ws_size;
    const float* x        = (const float*)d_in[0];
    const float* emb_mean = (const float*)d_in[1];
    const float* emb_std  = (const float*)d_in[2];
    const float* enc_w0 = (const float*)d_in[3];
    const float* enc_b0 = (const float*)d_in[4];
    const float* enc_g0 = (const float*)d_in[5];
    const float* enc_w1 = (const float*)d_in[6];
    const float* enc_b1 = (const float*)d_in[7];
    const float* enc_g1 = (const float*)d_in[8];
    const float* enc_w2 = (const float*)d_in[9];
    const float* enc_b2 = (const float*)d_in[10];
    const float* enc_g2 = (const float*)d_in[11];
    const float* cb     = (const float*)d_in[12];
    const float* dec_w0 = (const float*)d_in[13];
    const float* dec_b0 = (const float*)d_in[14];
    const float* dec_g0 = (const float*)d_in[15];
    const float* dec_w1 = (const float*)d_in[16];
    const float* dec_b1 = (const float*)d_in[17];
    const float* dec_g1 = (const float*)d_in[18];
    const float* dec_w2 = (const float*)d_in[19];
    const float* dec_b2 = (const float*)d_in[20];

    float* out   = (float*)d_out;
    float* xn    = out;                        // recon region doubles as xn scratch
    float* ids_f = out + (size_t)NB * DIN;     // 12582912
    float* rl    = out + (size_t)NB * DIN + (size_t)NB * 4;      // 12648448
    float* vl    = rl + 1;

    float* ws   = (float*)d_ws;
    float* h0   = ws;                           // 16384*512
    float* h1   = h0 + (size_t)NB * 512;        // 16384*256
    float* h2   = h1 + (size_t)NB * 256;        // 16384*128
    float* rbuf = h2 + (size_t)NB * 128;        // 16384*128
    float* qsum = rbuf + (size_t)NB * 128;      // 16384*128
    float* cbn  = qsum + (size_t)NB * 128;      // 4*8192
    int*   idxb = (int*)(cbn + 4 * 8192);       // 16384

    k_zero2<<<1, 64, 0, stream>>>(rl, vl);
    k_norm<<<(NB * DIN) / 256, 256, 0, stream>>>(x, emb_mean, emb_std, xn);
    k_cbnorm<<<(4 * 8192) / 4, 256, 0, stream>>>(cb, cbn);

    k_lin_relu_rms<512><<<NB / 32, 256, 0, stream>>>(xn, enc_w0, enc_b0, enc_g0, h0, 768);
    k_lin_relu_rms<256><<<NB / 32, 256, 0, stream>>>(h0, enc_w1, enc_b1, enc_g1, h1, 512);
    k_lin_relu_rms<128><<<NB / 32, 256, 0, stream>>>(h1, enc_w2, enc_b2, enc_g2, h2, 256);

    for (int q = 0; q < 4; q++) {
        const float* R = (q == 0) ? h2 : rbuf;
        const float* Eq = cb + (size_t)q * 8192 * 128;
        k_vq_argmin<<<NB / 64, 256, 0, stream>>>(R, Eq, cbn + q * 8192, idxb, ids_f + q);
        k_vq_update<<<(NB * 128) / 256, 256, 0, stream>>>(R, idxb, Eq, rbuf, qsum, vl, q == 0 ? 1 : 0);
    }

    k_lin_relu_rms<256><<<NB / 32, 256, 0, stream>>>(qsum, dec_w0, dec_b0, dec_g0, h1, 128);
    k_lin_relu_rms<512><<<NB / 32, 256, 0, stream>>>(h1, dec_w1, dec_b1, dec_g1, h0, 256);

    dim3 g2(NB / 64, DIN / 64);
    k_dec2<<<g2, 256, 0, stream>>>(h0, dec_w2, dec_b2, xn, rl);
}

// Round 4
// 5067.554 us; speedup vs baseline: 1.1790x; 1.1790x over previous
//
#include <hip/hip_runtime.h>
#include <math.h>

#define NB 16384
#define DIN 768

// ---------------- small kernels ----------------

__global__ void k_zero2(float* a, float* b) {
    if (threadIdx.x == 0) { *a = 0.f; *b = 0.f; }
}

__global__ void k_norm(const float* __restrict__ x, const float* __restrict__ m,
                       const float* __restrict__ s, float* __restrict__ xn) {
    int i = blockIdx.x * 256 + threadIdx.x;          // 16384*768 total
    int j = i % DIN;
    xn[i] = (x[i] - m[j]) / s[j];
}

// one 64-lane wave per codebook row (4 rows / 256-thread block)
__global__ void k_cbnorm(const float* __restrict__ cb, float* __restrict__ cbn) {
    int row = blockIdx.x * 4 + (threadIdx.x >> 6);
    int lane = threadIdx.x & 63;
    const float* p = cb + (size_t)row * 128;
    float v0 = p[lane], v1 = p[lane + 64];
    float s = v0 * v0 + v1 * v1;
    #pragma unroll
    for (int m = 32; m >= 1; m >>= 1) s += __shfl_xor(s, m, 64);
    if (lane == 0) cbn[row] = s;
}

// ---------------- fused Linear + ReLU + RMSNorm ----------------
// block = 32 rows x N cols; threads (tx=32, ty=8); per-thread 4 rows x N/32 cols
template <int N>
__global__ __launch_bounds__(256, 2) void k_lin_relu_rms(
    const float* __restrict__ A, const float* __restrict__ W,
    const float* __restrict__ bias, const float* __restrict__ g,
    float* __restrict__ out, int K) {
    constexpr int CJ = N / 32;
    __shared__ float Asub[32][17];
    __shared__ float Wsub[16][N];
    __shared__ float rsums[32];
    const int tid = threadIdx.x;
    const int tx = tid & 31, ty = tid >> 5;
    const int row0 = blockIdx.x * 32;

    float acc[4][CJ];
    #pragma unroll
    for (int r = 0; r < 4; r++)
        #pragma unroll
        for (int j = 0; j < CJ; j++) acc[r][j] = 0.f;

    for (int k0 = 0; k0 < K; k0 += 16) {
        for (int e = tid; e < 512; e += 256) {
            int r = e >> 4, kk = e & 15;
            Asub[r][kk] = A[(size_t)(row0 + r) * K + k0 + kk];
        }
        constexpr int NW4 = 16 * N / 4;
        for (int e = tid; e < NW4; e += 256) {
            int kk = e / (N / 4), c4 = e % (N / 4);
            *(float4*)&Wsub[kk][c4 * 4] = *(const float4*)&W[(size_t)(k0 + kk) * N + c4 * 4];
        }
        __syncthreads();
        #pragma unroll
        for (int kk = 0; kk < 16; kk++) {
            float a[4];
            #pragma unroll
            for (int r = 0; r < 4; r++) a[r] = Asub[ty * 4 + r][kk];
            #pragma unroll
            for (int j = 0; j < CJ; j++) {
                float w = Wsub[kk][tx + 32 * j];
                #pragma unroll
                for (int r = 0; r < 4; r++) acc[r][j] = fmaf(a[r], w, acc[r][j]);
            }
        }
        __syncthreads();
    }
    // bias + relu + per-row sum of squares
    float ss[4] = {0.f, 0.f, 0.f, 0.f};
    #pragma unroll
    for (int j = 0; j < CJ; j++) {
        float bb = bias[tx + 32 * j];
        #pragma unroll
        for (int r = 0; r < 4; r++) {
            float v = acc[r][j] + bb;
            v = v > 0.f ? v : 0.f;
            acc[r][j] = v;
            ss[r] = fmaf(v, v, ss[r]);
        }
    }
    #pragma unroll
    for (int m = 1; m < 32; m <<= 1)
        #pragma unroll
        for (int r = 0; r < 4; r++) ss[r] += __shfl_xor(ss[r], m, 64);
    if (tx == 0)
        #pragma unroll
        for (int r = 0; r < 4; r++) rsums[ty * 4 + r] = ss[r];
    __syncthreads();
    constexpr float invN = 1.0f / (float)N;
    #pragma unroll
    for (int r = 0; r < 4; r++) {
        float scale = 1.0f / sqrtf(rsums[ty * 4 + r] * invN + 1e-6f);
        #pragma unroll
        for (int j = 0; j < CJ; j++) {
            int col = tx + 32 * j;
            out[(size_t)(row0 + ty * 4 + r) * N + col] = acc[r][j] * scale * g[col];
        }
    }
}

// ---------------- VQ: exact fp32 score + partial argmin ----------------
// grid = (NB/64 row-blocks, 4 code-strips of 2048). block = 128 threads (2 waves),
// tx=16 codes, ty=8; micro-tile 8 rows x 8 codes. k contiguous in LDS -> b128 reads.
// Row mapping (read and writeback identical):
//   row = row0 + (m>>2)*32 + (ty>>2)*16 + (ty&3)*4 + (m&3)      [m = 0..7]
// Within a wave (ty>>2 const) lanes hit rows {c, c+4, c+8, c+12} -> 2-way bank
// aliasing, free per m136.
// s_k = ||E_k||^2 - 2*r.E_k (row-constant ||r||^2 dropped; argmin-equivalent)
#define CSTRIP 2048
__global__ __launch_bounds__(128, 2) void k_vq_argmin(
    const float* __restrict__ R, const float* __restrict__ E,
    const float* __restrict__ cbn,
    float* __restrict__ pbest, int* __restrict__ pidx) {
    __shared__ float Rs[64][132];   // stride 132 floats
    __shared__ float Es[128][36];   // stride 36: codes tx, tx+16j -> 2-way banks (free)
    const int tid = threadIdx.x;
    const int tx = tid & 15, ty = tid >> 4;           // ty 0..7
    const int row0 = blockIdx.x * 64;
    const int cbase = blockIdx.y * CSTRIP;
    const int rb = (ty >> 2) * 16 + (ty & 3) * 4;     // per-thread row base within 32

    // stage R tile 64x128 once (2048 float4, 16 per thread)
    for (int f = tid; f < 2048; f += 128) {
        int r = f >> 5, k4 = f & 31;
        *(float4*)&Rs[r][k4 * 4] = *(const float4*)&R[(size_t)(row0 + r) * 128 + k4 * 4];
    }

    float best[8];
    int bidx[8];
    #pragma unroll
    for (int m = 0; m < 8; m++) { best[m] = 3.402823466e+38f; bidx[m] = 0; }

    for (int cc = 0; cc < CSTRIP; cc += 128) {
        float acc[8][8];
        #pragma unroll
        for (int m = 0; m < 8; m++)
            #pragma unroll
            for (int j = 0; j < 8; j++) acc[m][j] = 0.f;

        for (int k0 = 0; k0 < 128; k0 += 32) {
            __syncthreads();   // prev compute done (also covers initial Rs stage)
            // stage E chunk [128 codes][32 k] (1024 float4, 8 per thread)
            for (int f = tid; f < 1024; f += 128) {
                int c = f >> 3, k4 = f & 7;
                *(float4*)&Es[c][k4 * 4] =
                    *(const float4*)&E[(size_t)(cbase + cc + c) * 128 + k0 + k4 * 4];
            }
            __syncthreads();
            #pragma unroll
            for (int k4 = 0; k4 < 8; k4++) {
                float4 a[8];
                #pragma unroll
                for (int h = 0; h < 2; h++)
                    #pragma unroll
                    for (int r = 0; r < 4; r++)
                        a[h * 4 + r] = *(const float4*)&Rs[h * 32 + rb + r][k0 + k4 * 4];
                #pragma unroll
                for (int j = 0; j < 8; j++) {
                    float4 e = *(const float4*)&Es[tx + 16 * j][k4 * 4];
                    #pragma unroll
                    for (int m = 0; m < 8; m++) {
                        acc[m][j] = fmaf(a[m].x, e.x, acc[m][j]);
                        acc[m][j] = fmaf(a[m].y, e.y, acc[m][j]);
                        acc[m][j] = fmaf(a[m].z, e.z, acc[m][j]);
                        acc[m][j] = fmaf(a[m].w, e.w, acc[m][j]);
                    }
                }
            }
        }
        // running argmin (per-thread code order ascending -> strict < keeps first)
        #pragma unroll
        for (int j = 0; j < 8; j++) {
            int c = cbase + cc + tx + 16 * j;
            float cn = cbn[c];
            #pragma unroll
            for (int m = 0; m < 8; m++) {
                float s = fmaf(-2.f, acc[m][j], cn);
                if (s < best[m]) { best[m] = s; bidx[m] = c; }
            }
        }
    }
    // reduce across the 16 tx lanes; tie -> smaller index (numpy first-occurrence)
    #pragma unroll
    for (int mask = 1; mask < 16; mask <<= 1) {
        #pragma unroll
        for (int m = 0; m < 8; m++) {
            float ob = __shfl_xor(best[m], mask, 64);
            int oi = __shfl_xor(bidx[m], mask, 64);
            if (ob < best[m] || (ob == best[m] && oi < bidx[m])) { best[m] = ob; bidx[m] = oi; }
        }
    }
    if (tx == 0) {
        #pragma unroll
        for (int m = 0; m < 8; m++) {
            int row = row0 + (m >> 2) * 32 + rb + (m & 3);
            pbest[(size_t)blockIdx.y * NB + row] = best[m];
            pidx[(size_t)blockIdx.y * NB + row] = bidx[m];
        }
    }
}

// merge the 4 strip-partials; tie -> smaller index
__global__ void k_vq_reduce(const float* __restrict__ pbest, const int* __restrict__ pidx,
                            int* __restrict__ idx_out, float* __restrict__ ids_f) {
    int row = blockIdx.x * 256 + threadIdx.x;
    float b = pbest[row];
    int bi = pidx[row];
    #pragma unroll
    for (int s = 1; s < 4; s++) {
        float ob = pbest[(size_t)s * NB + row];
        int oi = pidx[(size_t)s * NB + row];
        if (ob < b || (ob == b && oi < bi)) { b = ob; bi = oi; }
    }
    idx_out[row] = bi;
    ids_f[(size_t)row * 4] = (float)bi;
}

// gather + residual update + qsum + vq_loss partial
__global__ void k_vq_update(const float* __restrict__ Rin, const int* __restrict__ idx,
                            const float* __restrict__ E, float* __restrict__ Rout,
                            float* __restrict__ qsum, float* __restrict__ vq_acc,
                            int firstq) {
    __shared__ float ps[4];
    int i = blockIdx.x * 256 + threadIdx.x;   // NB*128 total
    int row = i >> 7, d = i & 127;
    float e = E[(size_t)idx[row] * 128 + d];
    float rv = Rin[i] - e;
    Rout[i] = rv;
    qsum[i] = firstq ? e : (qsum[i] + e);
    float p = rv * rv;
    #pragma unroll
    for (int m = 1; m < 64; m <<= 1) p += __shfl_xor(p, m, 64);
    int lane = threadIdx.x & 63, w = threadIdx.x >> 6;
    if (lane == 0) ps[w] = p;
    __syncthreads();
    if (threadIdx.x == 0)
        atomicAdd(vq_acc, (ps[0] + ps[1] + ps[2] + ps[3]) * (1.25f / ((float)NB * 128.f)));
}

// ---------------- final Linear (512->768) + recon loss ----------------
// 64x64 tile; threads (16,16); micro 4x4. Reads xn from rec[], overwrites with recon.
__global__ __launch_bounds__(256, 2) void k_dec2(
    const float* __restrict__ A, const float* __restrict__ W,
    const float* __restrict__ bias, float* __restrict__ rec,
    float* __restrict__ loss_acc) {
    __shared__ float Asub[64][17];
    __shared__ float Wsub[16][64];
    __shared__ float red[4];
    const int tid = threadIdx.x;
    const int tx = tid & 15, ty = tid >> 4;
    const int row0 = blockIdx.x * 64, col0 = blockIdx.y * 64;
    float acc[4][4];
    #pragma unroll
    for (int r = 0; r < 4; r++)
        #pragma unroll
        for (int j = 0; j < 4; j++) acc[r][j] = 0.f;

    for (int k0 = 0; k0 < 512; k0 += 16) {
        for (int e = tid; e < 1024; e += 256) {
            int r = e >> 4, kk = e & 15;
            Asub[r][kk] = A[(size_t)(row0 + r) * 512 + k0 + kk];
        }
        {
            int kk = tid >> 4, c = tid & 15;
            *(float4*)&Wsub[kk][c * 4] = *(const float4*)&W[(size_t)(k0 + kk) * DIN + col0 + c * 4];
        }
        __syncthreads();
        #pragma unroll
        for (int kk = 0; kk < 16; kk++) {
            float a[4], w[4];
            #pragma unroll
            for (int r = 0; r < 4; r++) a[r] = Asub[ty * 4 + r][kk];
            #pragma unroll
            for (int j = 0; j < 4; j++) w[j] = Wsub[kk][tx + 16 * j];
            #pragma unroll
            for (int r = 0; r < 4; r++)
                #pragma unroll
                for (int j = 0; j < 4; j++) acc[r][j] = fmaf(a[r], w[j], acc[r][j]);
        }
        __syncthreads();
    }
    float lsum = 0.f;
    #pragma unroll
    for (int j = 0; j < 4; j++) {
        int col = col0 + tx + 16 * j;
        float bb = bias[col];
        #pragma unroll
        for (int r = 0; r < 4; r++) {
            int row = row0 + ty * 4 + r;
            float v = acc[r][j] + bb;
            size_t o = (size_t)row * DIN + col;
            float e = v - rec[o];     // rec holds xn here
            lsum = fmaf(e, e, lsum);
            rec[o] = v;
        }
    }
    #pragma unroll
    for (int m = 1; m < 64; m <<= 1) lsum += __shfl_xor(lsum, m, 64);
    int lane = tid & 63, w = tid >> 6;
    if (lane == 0) red[w] = lsum;
    __syncthreads();
    if (tid == 0)
        atomicAdd(loss_acc, (red[0] + red[1] + red[2] + red[3]) * (1.0f / ((float)NB * (float)DIN)));
}

// ---------------- launch ----------------

extern "C" void kernel_launch(void* const* d_in, const int* in_sizes, int n_in,
                              void* d_out, int out_size, void* d_ws, size_t ws_size,
                              hipStream_t stream) {
    (void)in_sizes; (void)n_in; (void)out_size; (void)ws_size;
    const float* x        = (const float*)d_in[0];
    const float* emb_mean = (const float*)d_in[1];
    const float* emb_std  = (const float*)d_in[2];
    const float* enc_w0 = (const float*)d_in[3];
    const float* enc_b0 = (const float*)d_in[4];
    const float* enc_g0 = (const float*)d_in[5];
    const float* enc_w1 = (const float*)d_in[6];
    const float* enc_b1 = (const float*)d_in[7];
    const float* enc_g1 = (const float*)d_in[8];
    const float* enc_w2 = (const float*)d_in[9];
    const float* enc_b2 = (const float*)d_in[10];
    const float* enc_g2 = (const float*)d_in[11];
    const float* cb     = (const float*)d_in[12];
    const float* dec_w0 = (const float*)d_in[13];
    const float* dec_b0 = (const float*)d_in[14];
    const float* dec_g0 = (const float*)d_in[15];
    const float* dec_w1 = (const float*)d_in[16];
    const float* dec_b1 = (const float*)d_in[17];
    const float* dec_g1 = (const float*)d_in[18];
    const float* dec_w2 = (const float*)d_in[19];
    const float* dec_b2 = (const float*)d_in[20];

    float* out   = (float*)d_out;
    float* xn    = out;                        // recon region doubles as xn scratch
    float* ids_f = out + (size_t)NB * DIN;     // 12582912
    float* rl    = out + (size_t)NB * DIN + (size_t)NB * 4;      // 12648448
    float* vl    = rl + 1;

    float* ws   = (float*)d_ws;
    float* h0   = ws;                           // 16384*512
    float* h1   = h0 + (size_t)NB * 512;        // 16384*256
    float* h2   = h1 + (size_t)NB * 256;        // 16384*128
    float* rbuf = h2 + (size_t)NB * 128;        // 16384*128
    float* qsum = rbuf + (size_t)NB * 128;      // 16384*128
    float* cbn  = qsum + (size_t)NB * 128;      // 4*8192
    int*   idxb = (int*)(cbn + 4 * 8192);       // 16384

    // strip-partial argmin buffers live in h0 (free between encoder and decoder)
    float* pbest = h0;                          // 4*16384 floats
    int*   pidx  = (int*)(h0 + 4 * (size_t)NB); // 4*16384 ints

    k_zero2<<<1, 64, 0, stream>>>(rl, vl);
    k_norm<<<(NB * DIN) / 256, 256, 0, stream>>>(x, emb_mean, emb_std, xn);
    k_cbnorm<<<(4 * 8192) / 4, 256, 0, stream>>>(cb, cbn);

    k_lin_relu_rms<512><<<NB / 32, 256, 0, stream>>>(xn, enc_w0, enc_b0, enc_g0, h0, 768);
    k_lin_relu_rms<256><<<NB / 32, 256, 0, stream>>>(h0, enc_w1, enc_b1, enc_g1, h1, 512);
    k_lin_relu_rms<128><<<NB / 32, 256, 0, stream>>>(h1, enc_w2, enc_b2, enc_g2, h2, 256);

    for (int q = 0; q < 4; q++) {
        const float* R = (q == 0) ? h2 : rbuf;
        const float* Eq = cb + (size_t)q * 8192 * 128;
        dim3 gq(NB / 64, 4);
        k_vq_argmin<<<gq, 128, 0, stream>>>(R, Eq, cbn + q * 8192, pbest, pidx);
        k_vq_reduce<<<NB / 256, 256, 0, stream>>>(pbest, pidx, idxb, ids_f + q);
        k_vq_update<<<(NB * 128) / 256, 256, 0, stream>>>(R, idxb, Eq, rbuf, qsum, vl, q == 0 ? 1 : 0);
    }

    k_lin_relu_rms<256><<<NB / 32, 256, 0, stream>>>(qsum, dec_w0, dec_b0, dec_g0, h1, 128);
    k_lin_relu_rms<512><<<NB / 32, 256, 0, stream>>>(h1, dec_w1, dec_b1, dec_g1, h0, 256);

    dim3 g2(NB / 64, DIN / 64);
    k_dec2<<<g2, 256, 0, stream>>>(h0, dec_w2, dec_b2, xn, rl);
}